// Round 21
// baseline (1329.370 us; speedup 1.0000x reference)
//
#include <hip/hip_runtime.h>
#include <cstdint>
#include <cstddef>

#define HWSZ 65536  // 256*256

typedef float v2f __attribute__((ext_vector_type(2)));

__device__ __forceinline__ uint32_t f2bfu(float f) {
  union { float f; uint32_t u; } v; v.f = f;
  return (v.u + 0x7FFFu + ((v.u >> 16) & 1u)) >> 16;  // RNE bf16, as uint
}
__device__ __forceinline__ float bfhi(uint32_t u) {  // high bf16 of pair
  union { uint32_t u; float f; } v; v.u = u & 0xffff0000u;
  return v.f;
}
__device__ __forceinline__ float bflo(uint32_t u) {  // low bf16 of pair
  union { uint32_t u; float f; } v; v.u = u << 16;
  return v.f;
}

// ---------------- K0: spatial kernel from rfft2 filter --------------------
__global__ void k_prep(const float* __restrict__ F, float* __restrict__ Ks) {
  __shared__ float ct[8];
  int t = threadIdx.x;
  int c = blockIdx.x;
  if (t == 0) {
    const float r2 = 0.70710678118654752f;
    ct[0] = 1.f; ct[1] = r2; ct[2] = 0.f; ct[3] = -r2;
    ct[4] = -1.f; ct[5] = -r2; ct[6] = 0.f; ct[7] = r2;
  }
  __syncthreads();
  int p = t >> 3, q = t & 7;
  const float* Fc = F + c * 40;
  float s = 0.f;
#pragma unroll
  for (int u = 0; u < 8; ++u) {
#pragma unroll
    for (int v = 0; v < 8; ++v) {
      float g = (v <= 4) ? Fc[u * 5 + v] : Fc[((8 - u) & 7) * 5 + (8 - v)];
      s += g * ct[(u * p + v * q) & 7];
    }
  }
  Ks[c * 64 + t] = s * (1.f / 64.f);
}

// ---------------- K0b: transpose w_out [64][256] -> wT [256][64] ----------
__global__ void k_wt(const float* __restrict__ w_out, float* __restrict__ wT) {
  int c = blockIdx.x;   // 256
  int d = threadIdx.x;  // 64
  wT[c * 64 + d] = w_out[d * 256 + c];
}

// ---------------- K0c: pack w_dw 49 -> 64-stride (8-aligned taps) ---------
__global__ void k_wdw(const float* __restrict__ w_dw,
                      const float* __restrict__ b_dw,
                      float* __restrict__ wdwp) {
  int c = blockIdx.x;   // 256
  int t = threadIdx.x;  // 64
  int u = t >> 3, k = t & 7;
  float v = 0.f;
  if (t == 55) v = b_dw[c];
  else if (t < 56 && k < 7) v = w_dw[c * 49 + u * 7 + k];
  wdwp[c * 64 + t] = v;
}

// ---------------- K0d: exact-GELU lookup table, 1024 bins over [-6,6] -----
__global__ void k_gt(float2* __restrict__ gtab) {
  int i = blockIdx.x * 256 + threadIdx.x;  // 0..1023
  const float h = 0.01171875f;             // 12/1024 exact
  const float RS2 = 0.70710678118654752f;
  float x0 = -6.f + i * h;
  float x1 = x0 + h;
  float v0 = 0.5f * x0 * (1.f + erff(x0 * RS2));
  float v1 = 0.5f * x1 * (1.f + erff(x1 * RS2));
  float2 e; e.x = v0; e.y = v1 - v0;
  gtab[i] = e;
}

// circular 8x8 conv, 2 output rows (sq*2, sq*2+1) of one channel.
__device__ __forceinline__ void circ4(const uint32_t* __restrict__ prb,
                                      const float* __restrict__ kc, int sq,
                                      uint32_t* __restrict__ ou) {
  float o[16];
#pragma unroll
  for (int t = 0; t < 16; ++t) o[t] = 0.f;
#pragma unroll 1
  for (int tph = 0; tph < 2; ++tph) {
    float kh[32];
#pragma unroll
    for (int q4 = 0; q4 < 8; ++q4) {
      float4 kv = *(const float4*)(kc + tph * 32 + q4 * 4);
      kh[q4 * 4 + 0] = kv.x; kh[q4 * 4 + 1] = kv.y;
      kh[q4 * 4 + 2] = kv.z; kh[q4 * 4 + 3] = kv.w;
    }
#pragma unroll
    for (int ii = 0; ii < 2; ++ii) {
      int i = sq * 2 + ii;
#pragma unroll
      for (int t4 = 0; t4 < 4; ++t4) {
        int tp = tph * 4 + t4;
        int r = (i - tp) & 7;
        uint2 ua = *(const uint2*)(prb + r * 4);
        uint2 ub = *(const uint2*)(prb + r * 4 + 2);
        float pr[8] = {bflo(ua.x), bfhi(ua.x), bflo(ua.y), bfhi(ua.y),
                       bflo(ub.x), bfhi(ub.x), bflo(ub.y), bfhi(ub.y)};
#pragma unroll
        for (int tq = 0; tq < 8; ++tq) {
          float kv = kh[t4 * 8 + tq];
#pragma unroll
          for (int j = 0; j < 8; ++j)
            o[ii * 8 + j] += kv * pr[(j - tq) & 7];
        }
      }
    }
  }
#pragma unroll
  for (int ii = 0; ii < 2; ++ii) {
    ou[ii * 4 + 0] = f2bfu(o[ii * 8 + 0]) | (f2bfu(o[ii * 8 + 1]) << 16);
    ou[ii * 4 + 1] = f2bfu(o[ii * 8 + 2]) | (f2bfu(o[ii * 8 + 3]) << 16);
    ou[ii * 4 + 2] = f2bfu(o[ii * 8 + 4]) | (f2bfu(o[ii * 8 + 5]) << 16);
    ou[ii * 4 + 3] = f2bfu(o[ii * 8 + 6]) | (f2bfu(o[ii * 8 + 7]) << 16);
  }
}

// ---------------- K1 v9: conv_in 1x1 + bias + patch circular conv ---------
// QUAD-SPLIT (verified R16: ~320us). Unchanged.
__global__ __launch_bounds__(256, 2) void k_front(
    const float* __restrict__ x, const float* __restrict__ w_in,
    const float* __restrict__ b_in, const float* __restrict__ Ks,
    uint32_t* __restrict__ midu) {
  __shared__ __align__(16) uint32_t Au[128 * 34];  // x floats, then ch 0-127
  __shared__ __align__(16) uint32_t Bu[128 * 34];  // ch 128-255
  float* xs = (float*)Au;  // 4096 floats during phases 1-2
  int tid = threadIdx.x;
  int orig = blockIdx.x;
  int pid = (orig & 7) * 1024 + (orig >> 3);  // XCD swizzle (8192 % 8 == 0)
  int b = pid >> 10;
  int pp = pid & 1023;
  int ph = pp >> 5, pw = pp & 31;

  // phase 1: stage x patch (4096 floats) cooperatively, coalesced float4
  {
    const float* xb = x + (size_t)b * 64 * HWSZ + (ph * 8) * 256 + pw * 8;
#pragma unroll
    for (int k = 0; k < 4; ++k) {
      int s = tid + k * 256;
      int d = s >> 4, i = (s >> 1) & 7, jh = s & 1;
      float4 v = *(const float4*)(xb + (size_t)d * HWSZ + i * 256 + jh * 4);
      *(float4*)(xs + d * 64 + i * 8 + jh * 4) = v;
    }
  }
  int sq = tid & 3;   // px quarter: rows sq*2, sq*2+1
  int cq = tid >> 2;  // 0..63
  float p0[16], p1[16], p2[16], p3[16];
  {
    float bi0 = b_in[cq], bi1 = b_in[cq + 64];
    float bi2 = b_in[cq + 128], bi3 = b_in[cq + 192];
#pragma unroll
    for (int t = 0; t < 16; ++t) {
      p0[t] = bi0; p1[t] = bi1; p2[t] = bi2; p3[t] = bi3;
    }
  }
  __syncthreads();

  // phase 2: conv_in, 4 channels x 16 px (1 xs read -> 16 FMA)
  const float* w0 = w_in + cq * 64;
  const float* w1 = w_in + (cq + 64) * 64;
  const float* w2 = w_in + (cq + 128) * 64;
  const float* w3 = w_in + (cq + 192) * 64;
#pragma unroll 1
  for (int d8 = 0; d8 < 8; ++d8) {
    float4 a0 = *(const float4*)(w0 + d8 * 8);
    float4 b0 = *(const float4*)(w0 + d8 * 8 + 4);
    float4 a1 = *(const float4*)(w1 + d8 * 8);
    float4 b1 = *(const float4*)(w1 + d8 * 8 + 4);
    float4 a2 = *(const float4*)(w2 + d8 * 8);
    float4 b2 = *(const float4*)(w2 + d8 * 8 + 4);
    float4 a3 = *(const float4*)(w3 + d8 * 8);
    float4 b3 = *(const float4*)(w3 + d8 * 8 + 4);
    float wv0[8] = {a0.x, a0.y, a0.z, a0.w, b0.x, b0.y, b0.z, b0.w};
    float wv1[8] = {a1.x, a1.y, a1.z, a1.w, b1.x, b1.y, b1.z, b1.w};
    float wv2[8] = {a2.x, a2.y, a2.z, a2.w, b2.x, b2.y, b2.z, b2.w};
    float wv3[8] = {a3.x, a3.y, a3.z, a3.w, b3.x, b3.y, b3.z, b3.w};
#pragma unroll
    for (int dd = 0; dd < 8; ++dd) {
      const float4* xr = (const float4*)(xs + (d8 * 8 + dd) * 64 + sq * 16);
#pragma unroll
      for (int t4 = 0; t4 < 4; ++t4) {
        float4 xv = xr[t4];
        p0[t4 * 4 + 0] += wv0[dd] * xv.x; p1[t4 * 4 + 0] += wv1[dd] * xv.x;
        p2[t4 * 4 + 0] += wv2[dd] * xv.x; p3[t4 * 4 + 0] += wv3[dd] * xv.x;
        p0[t4 * 4 + 1] += wv0[dd] * xv.y; p1[t4 * 4 + 1] += wv1[dd] * xv.y;
        p2[t4 * 4 + 1] += wv2[dd] * xv.y; p3[t4 * 4 + 1] += wv3[dd] * xv.y;
        p0[t4 * 4 + 2] += wv0[dd] * xv.z; p1[t4 * 4 + 2] += wv1[dd] * xv.z;
        p2[t4 * 4 + 2] += wv2[dd] * xv.z; p3[t4 * 4 + 2] += wv3[dd] * xv.z;
        p0[t4 * 4 + 3] += wv0[dd] * xv.w; p1[t4 * 4 + 3] += wv1[dd] * xv.w;
        p2[t4 * 4 + 3] += wv2[dd] * xv.w; p3[t4 * 4 + 3] += wv3[dd] * xv.w;
      }
    }
  }
  __syncthreads();  // all conv_in reads of xs done before bf16 overwrite

  // phase 3: pack p -> bf16 pairs into channel rows (8 uints @ sq*8)
  {
    uint32_t* r0 = Au + cq * 34 + sq * 8;
    uint32_t* r1 = Au + (cq + 64) * 34 + sq * 8;
    uint32_t* r2 = Bu + cq * 34 + sq * 8;
    uint32_t* r3 = Bu + (cq + 64) * 34 + sq * 8;
#pragma unroll
    for (int m = 0; m < 4; ++m) {
      uint2 u0, u1, u2, u3;
      u0.x = f2bfu(p0[m * 4 + 0]) | (f2bfu(p0[m * 4 + 1]) << 16);
      u0.y = f2bfu(p0[m * 4 + 2]) | (f2bfu(p0[m * 4 + 3]) << 16);
      u1.x = f2bfu(p1[m * 4 + 0]) | (f2bfu(p1[m * 4 + 1]) << 16);
      u1.y = f2bfu(p1[m * 4 + 2]) | (f2bfu(p1[m * 4 + 3]) << 16);
      u2.x = f2bfu(p2[m * 4 + 0]) | (f2bfu(p2[m * 4 + 1]) << 16);
      u2.y = f2bfu(p2[m * 4 + 2]) | (f2bfu(p2[m * 4 + 3]) << 16);
      u3.x = f2bfu(p3[m * 4 + 0]) | (f2bfu(p3[m * 4 + 1]) << 16);
      u3.y = f2bfu(p3[m * 4 + 2]) | (f2bfu(p3[m * 4 + 3]) << 16);
      *(uint2*)(r0 + m * 2) = u0;
      *(uint2*)(r1 + m * 2) = u1;
      *(uint2*)(r2 + m * 2) = u2;
      *(uint2*)(r3 + m * 2) = u3;
    }
  }
  __syncthreads();  // all p rows visible before circ conv

  // phase 4: circ conv, 4 channels sequential; ONE barrier, then write-back
  uint32_t ou[4][8];
  circ4(Au + cq * 34, Ks + cq * 64, sq, ou[0]);
  circ4(Au + (cq + 64) * 34, Ks + (cq + 64) * 64, sq, ou[1]);
  circ4(Bu + cq * 34, Ks + (cq + 128) * 64, sq, ou[2]);
  circ4(Bu + (cq + 64) * 34, Ks + (cq + 192) * 64, sq, ou[3]);
  __syncthreads();  // all reads of Au/Bu complete
  {
    uint32_t* r0 = Au + cq * 34 + sq * 8;
    uint32_t* r1 = Au + (cq + 64) * 34 + sq * 8;
    uint32_t* r2 = Bu + cq * 34 + sq * 8;
    uint32_t* r3 = Bu + (cq + 64) * 34 + sq * 8;
#pragma unroll
    for (int m = 0; m < 4; ++m) {
      uint2 u0; u0.x = ou[0][m * 2 + 0]; u0.y = ou[0][m * 2 + 1];
      uint2 u1; u1.x = ou[1][m * 2 + 0]; u1.y = ou[1][m * 2 + 1];
      uint2 u2; u2.x = ou[2][m * 2 + 0]; u2.y = ou[2][m * 2 + 1];
      uint2 u3; u3.x = ou[3][m * 2 + 0]; u3.y = ou[3][m * 2 + 1];
      *(uint2*)(r0 + m * 2) = u0;
      *(uint2*)(r1 + m * 2) = u1;
      *(uint2*)(r2 + m * 2) = u2;
      *(uint2*)(r3 + m * 2) = u3;
    }
  }
  __syncthreads();

  // phase 6: cooperative fully-coalesced write: 8192 uints (32 KB) / block
  uint32_t* gbase = midu + (size_t)(b * 1024 + pp) * 8192;
#pragma unroll
  for (int k = 0; k < 8; ++k) {
    int g = tid * 4 + k * 1024;
    int w = g & 31;
    uint2 a, e;
    if (k < 4) {  // channels 0..127 live in Au (uniform branch: k static)
      int cc = g >> 5;
      a = *(uint2*)(Au + cc * 34 + w);
      e = *(uint2*)(Au + cc * 34 + w + 2);
    } else {      // channels 128..255 in Bu
      int cc = (g >> 5) - 128;
      a = *(uint2*)(Bu + cc * 34 + w);
      e = *(uint2*)(Bu + cc * 34 + w + 2);
    }
    uint4 q; q.x = a.x; q.y = a.y; q.z = e.x; q.w = e.y;
    *(uint4*)(gbase + g) = q;
  }
}

// ---------------- K2 v16: setprio compute + split dw chains --------------
// R20 structure (4 buffers, 2 ch/barrier, 869us ~ R18's 865; VGPR 104).
// Two register-free latency levers (everything issue-count-shaped is
// exhausted: readlane x, pk_fma 0, barrier-halving 0, d-split x):
//  (a) s_setprio(1) around the compute phase: 2 INDEPENDENT blocks/CU at
//      different phases -> scheduler can favor the compute-ready wave
//      (T5 prerequisite satisfied; +4-7% on phase-diverse structures).
//  (b) dw accumulation split into 2 partial chains per pixel (s0/s0b,
//      s1/s1b): halves the serial-add depth. +2 VGPR (margin 22).
//      Reassociation: ~1e-7 fp shift, far under tolerance.
#define TUB 48
__global__ __launch_bounds__(256, 1) void k_back(
    const uint32_t* __restrict__ midu, const float* __restrict__ wdwp,
    const float* __restrict__ wT, const float* __restrict__ b_out,
    const float2* __restrict__ gtab, float* __restrict__ out) {
  __shared__ __align__(16) uint32_t tile[4][22 * TUB];  // 16896 B
  __shared__ __align__(16) float wbuf[4][128];  // [0..63]=wdwp, [64..127]=wT
  __shared__ __align__(16) float2 gt[1024];     // 8192 B gelu table
  int t = threadIdx.x;
  int orig = blockIdx.x;
  int pid = (orig & 7) * 128 + (orig >> 3);  // XCD swizzle (1024 % 8 == 0)
  int b = pid >> 7;
  int tb = pid & 127;
  int th = tb >> 3, tw = tb & 7;  // 16 row-tiles x 8 col-tiles
  int R0 = th * 16, C0 = tw * 32;

  // copy gelu table to LDS (coalesced, one-time)
#pragma unroll
  for (int i = 0; i < 4; ++i) gt[t + i * 256] = gtab[t + i * 256];

  // zero-init all tile buffers; out-of-image slots stay zero
  for (int z = t; z < 4 * 22 * TUB; z += 256) ((uint32_t*)tile)[z] = 0u;

  // tile loader lanes: t<176: lr = t>>3 (row 0..21), p = t&7 (quad idx)
  int lr = t >> 3, p = t & 7;
  int g = R0 - 3 + lr;          // global px row
  int pc = 4 * tw - 1 + p;      // global patch col of own quad
  bool aw = (t < 176) && (p < 6) && ((unsigned)g < 256u);  // writer lane
  bool qv = aw && ((unsigned)pc < 32u);                    // own quad valid
  size_t src0 = 0;
  if (qv)
    src0 = ((size_t)(b * 1024 + (g >> 3) * 32 + pc) * 8192) +
           (size_t)((g & 7) * 4);

  int ty = t >> 4, tx = t & 15;
  int lane = t - 192;  // wave-3 lane id (valid when t >= 192)

  v2f acc[64];
#pragma unroll
  for (int d = 0; d < 64; ++d) acc[d] = (v2f)(0.f);

  __syncthreads();  // zero-init + table copy complete before prologue

  // prologue: stage channels 0 and 1 (tiles by t<176; weights by wave 3)
#pragma unroll 1
  for (int s = 0; s < 2; ++s) {
    uint4 q; q.x = 0u; q.y = 0u; q.z = 0u; q.w = 0u;
    if (qv) q = *(const uint4*)(midu + src0 + (size_t)s * 32);
    uint32_t ex = (uint32_t)__shfl_down((int)q.x, 1);  // neighbor quad word0
    if (aw) {
      uint32_t* dr = &tile[s][0] + lr * TUB;
      uint32_t w0 = (q.x >> 16) | (q.y << 16);  // k = 4p-2
      uint32_t w1 = (q.y >> 16) | (q.z << 16);  // k = 4p-1
      uint32_t w2 = (q.z >> 16) | (q.w << 16);  // k = 4p
      uint32_t w3 = (q.w >> 16) | (ex << 16);   // k = 4p+1
      if (p == 0) {
        uint2 hb; hb.x = w2; hb.y = w3;   // k = 0,1
        *(uint2*)(dr + 0) = hb;
      } else if (p == 5) {
        dr[18] = w0;                      // k = 18
      } else {
        uint2 ha; ha.x = w0; ha.y = w1;
        uint2 hb; hb.x = w2; hb.y = w3;
        *(uint2*)(dr + 4 * p - 2) = ha;   // k = 4p-2, 4p-1
        *(uint2*)(dr + 4 * p) = hb;       // k = 4p,   4p+1
      }
    }
    if (t >= 192) {  // wave-uniform: whole wave 3
      __builtin_amdgcn_global_load_lds(
          (const __attribute__((address_space(1))) uint32_t*)
              (wdwp + s * 64 + lane),
          (__attribute__((address_space(3))) uint32_t*)&wbuf[s][0], 4, 0, 0);
      __builtin_amdgcn_global_load_lds(
          (const __attribute__((address_space(1))) uint32_t*)
              (wT + s * 64 + lane),
          (__attribute__((address_space(3))) uint32_t*)&wbuf[s][64], 4, 0, 0);
    }
  }
  __syncthreads();

  for (int c = 0; c < 256; c += 2) {
    bool pf = (c < 254);  // uniform
    // prefetch channels c+2, c+3 (tiles to regs; weights DMA)
    uint4 qa, qb;
    qa.x = 0u; qa.y = 0u; qa.z = 0u; qa.w = 0u;
    qb = qa;
    if (pf && qv) {
      qa = *(const uint4*)(midu + src0 + (size_t)(c + 2) * 32);
      qb = *(const uint4*)(midu + src0 + (size_t)(c + 3) * 32);
    }
    if (pf && t >= 192) {
#pragma unroll
      for (int s = 0; s < 2; ++s) {
        int ch = c + 2 + s;
        int bi = ch & 3;
        __builtin_amdgcn_global_load_lds(
            (const __attribute__((address_space(1))) uint32_t*)
                (wdwp + (size_t)ch * 64 + lane),
            (__attribute__((address_space(3))) uint32_t*)&wbuf[bi][0],
            4, 0, 0);
        __builtin_amdgcn_global_load_lds(
            (const __attribute__((address_space(1))) uint32_t*)
                (wT + (size_t)ch * 64 + lane),
            (__attribute__((address_space(3))) uint32_t*)&wbuf[bi][64],
            4, 0, 0);
      }
    }

    // compute channels c and c+1 under elevated wave priority
    __builtin_amdgcn_s_setprio(1);
#pragma unroll 1
    for (int k2 = 0; k2 < 2; ++k2) {
      int bi = (c + k2) & 3;
      const uint32_t* tl = &tile[bi][0];
      const float* wl = &wbuf[bi][0];
      float s0 = wl[55], s1 = s0;   // bias (broadcast ds_read)
      float s0b = 0.f, s1b = 0.f;   // second partial chains
#pragma unroll
      for (int u = 0; u < 7; ++u) {
        const uint32_t* row = tl + (ty + u) * TUB + tx;
        uint32_t k0 = row[0], k1 = row[1], k2r = row[2], k3 = row[3];
        float f0 = bflo(k0), f1 = bfhi(k0), f2 = bflo(k1), f3 = bfhi(k1);
        float f4 = bflo(k2r), f5 = bfhi(k2r), f6 = bflo(k3), f7 = bfhi(k3);
        float4 wA = *(const float4*)(wl + u * 8);      // taps 0-3
        float4 wB = *(const float4*)(wl + u * 8 + 4);  // taps 4-6 + pad
        s0 += wA.x * f0 + wA.y * f1 + wA.z * f2 + wA.w * f3;
        s0b += wB.x * f4 + wB.y * f5 + wB.z * f6;
        s1 += wA.x * f1 + wA.y * f2 + wA.z * f3 + wA.w * f4;
        s1b += wB.x * f5 + wB.y * f6 + wB.z * f7;
      }
      s0 += s0b;
      s1 += s1b;
      // GELU via LDS table: idx = s*(1024/12)+512, linear interp
      const float GSC = 85.333333333333f;  // 1024/12
      float u0 = fminf(fmaxf(fmaf(s0, GSC, 512.f), 0.f), 1023.f);
      float u1 = fminf(fmaxf(fmaf(s1, GSC, 512.f), 0.f), 1023.f);
      int i0 = (int)u0, i1 = (int)u1;
      float2 e0 = gt[i0];
      float2 e1 = gt[i1];
      v2f g2;
      g2.x = fmaf(e0.y, u0 - (float)i0, e0.x);
      g2.y = fmaf(e1.y, u1 - (float)i1, e1.x);

      // conv_out: v_pk_fma_f32 — one instruction covers both pixels
      const float* wcl = wl + 64;
#pragma unroll
      for (int d4 = 0; d4 < 16; ++d4) {
        float4 wv = *(const float4*)(wcl + d4 * 4);
        acc[d4 * 4 + 0] += g2 * wv.x;
        acc[d4 * 4 + 1] += g2 * wv.y;
        acc[d4 * 4 + 2] += g2 * wv.z;
        acc[d4 * 4 + 3] += g2 * wv.w;
      }
    }
    __builtin_amdgcn_s_setprio(0);

    if (pf) {
      // write prefetched tiles c+2 (qa) and c+3 (qb)
      uint32_t exa = (uint32_t)__shfl_down((int)qa.x, 1);
      uint32_t exb = (uint32_t)__shfl_down((int)qb.x, 1);
      if (aw) {
#pragma unroll
        for (int s = 0; s < 2; ++s) {
          uint4 q = s ? qb : qa;
          uint32_t ex = s ? exb : exa;
          uint32_t* dr = &tile[(c + 2 + s) & 3][0] + lr * TUB;
          uint32_t w0 = (q.x >> 16) | (q.y << 16);
          uint32_t w1 = (q.y >> 16) | (q.z << 16);
          uint32_t w2 = (q.z >> 16) | (q.w << 16);
          uint32_t w3 = (q.w >> 16) | (ex << 16);
          if (p == 0) {
            uint2 hb; hb.x = w2; hb.y = w3;
            *(uint2*)(dr + 0) = hb;
          } else if (p == 5) {
            dr[18] = w0;
          } else {
            uint2 ha; ha.x = w0; ha.y = w1;
            uint2 hb; hb.x = w2; hb.y = w3;
            *(uint2*)(dr + 4 * p - 2) = ha;
            *(uint2*)(dr + 4 * p) = hb;
          }
        }
      }
    }
    __syncthreads();  // tiles+weights for c+2,c+3 ready; bufs c,c+1 free
  }

  // coalesced 8B stores: lanes cover consecutive spans of each row
  size_t obase = (size_t)b * 64 * HWSZ + (size_t)(R0 + ty) * 256 + C0 + 2 * tx;
#pragma unroll
  for (int d = 0; d < 64; ++d) {
    v2f r = acc[d] + b_out[d];  // b_out uniform -> s_load; packed add
    *(v2f*)(out + obase + (size_t)d * HWSZ) = r;
  }
}

extern "C" void kernel_launch(void* const* d_in, const int* in_sizes, int n_in,
                              void* d_out, int out_size, void* d_ws, size_t ws_size,
                              hipStream_t stream) {
  (void)in_sizes; (void)n_in; (void)out_size; (void)ws_size;
  const float* x     = (const float*)d_in[0];
  const float* w_in  = (const float*)d_in[1];
  const float* b_in  = (const float*)d_in[2];
  const float* fftf  = (const float*)d_in[3];
  const float* w_dw  = (const float*)d_in[4];
  const float* b_dw  = (const float*)d_in[5];
  const float* w_out = (const float*)d_in[6];
  const float* b_out = (const float*)d_in[7];
  float* out = (float*)d_out;

  float* Ks = (float*)d_ws;                                   // 64 KB
  float* wT = (float*)((char*)d_ws + 65536);                  // 64 KB
  float* wdwp = (float*)((char*)d_ws + 131072);               // 64 KB
  float2* gtab = (float2*)((char*)d_ws + 196608);             // 8 KB
  uint32_t* midu = (uint32_t*)((char*)d_ws + 204800);         // 268 MB

  k_prep<<<256, 64, 0, stream>>>(fftf, Ks);
  k_wt<<<256, 64, 0, stream>>>(w_out, wT);
  k_wdw<<<256, 64, 0, stream>>>(w_dw, b_dw, wdwp);
  k_gt<<<4, 256, 0, stream>>>(gtab);
  k_front<<<8192, 256, 0, stream>>>(x, w_in, b_in, Ks, midu);
  k_back<<<1024, 256, 0, stream>>>(midu, wdwp, wT, b_out, gtab, out);
}

// Round 22
// 1204.069 us; speedup vs baseline: 1.1041x; 1.1041x over previous
//
#include <hip/hip_runtime.h>
#include <cstdint>
#include <cstddef>

#define HWSZ 65536  // 256*256

typedef float v2f __attribute__((ext_vector_type(2)));

__device__ __forceinline__ uint32_t f2bfu(float f) {
  union { float f; uint32_t u; } v; v.f = f;
  return (v.u + 0x7FFFu + ((v.u >> 16) & 1u)) >> 16;  // RNE bf16, as uint
}
__device__ __forceinline__ float bfhi(uint32_t u) {  // high bf16 of pair
  union { uint32_t u; float f; } v; v.u = u & 0xffff0000u;
  return v.f;
}
__device__ __forceinline__ float bflo(uint32_t u) {  // low bf16 of pair
  union { uint32_t u; float f; } v; v.u = u << 16;
  return v.f;
}

// ---------------- K0: spatial kernel from rfft2 filter --------------------
__global__ void k_prep(const float* __restrict__ F, float* __restrict__ Ks) {
  __shared__ float ct[8];
  int t = threadIdx.x;
  int c = blockIdx.x;
  if (t == 0) {
    const float r2 = 0.70710678118654752f;
    ct[0] = 1.f; ct[1] = r2; ct[2] = 0.f; ct[3] = -r2;
    ct[4] = -1.f; ct[5] = -r2; ct[6] = 0.f; ct[7] = r2;
  }
  __syncthreads();
  int p = t >> 3, q = t & 7;
  const float* Fc = F + c * 40;
  float s = 0.f;
#pragma unroll
  for (int u = 0; u < 8; ++u) {
#pragma unroll
    for (int v = 0; v < 8; ++v) {
      float g = (v <= 4) ? Fc[u * 5 + v] : Fc[((8 - u) & 7) * 5 + (8 - v)];
      s += g * ct[(u * p + v * q) & 7];
    }
  }
  Ks[c * 64 + t] = s * (1.f / 64.f);
}

// ---------------- K0b: transpose w_out [64][256] -> wT [256][64] ----------
__global__ void k_wt(const float* __restrict__ w_out, float* __restrict__ wT) {
  int c = blockIdx.x;   // 256
  int d = threadIdx.x;  // 64
  wT[c * 64 + d] = w_out[d * 256 + c];
}

// ---------------- K0c: pack w_dw 49 -> 64-stride (8-aligned taps) ---------
__global__ void k_wdw(const float* __restrict__ w_dw,
                      const float* __restrict__ b_dw,
                      float* __restrict__ wdwp) {
  int c = blockIdx.x;   // 256
  int t = threadIdx.x;  // 64
  int u = t >> 3, k = t & 7;
  float v = 0.f;
  if (t == 55) v = b_dw[c];
  else if (t < 56 && k < 7) v = w_dw[c * 49 + u * 7 + k];
  wdwp[c * 64 + t] = v;
}

// ---------------- K0d: exact-GELU lookup table, 1024 bins over [-6,6] -----
// gtab[i] = {gelu(x_i), gelu(x_{i+1}) - gelu(x_i)}, x_i = -6 + i*(12/1024).
__global__ void k_gt(float2* __restrict__ gtab) {
  int i = blockIdx.x * 256 + threadIdx.x;  // 0..1023
  const float h = 0.01171875f;             // 12/1024 exact
  const float RS2 = 0.70710678118654752f;
  float x0 = -6.f + i * h;
  float x1 = x0 + h;
  float v0 = 0.5f * x0 * (1.f + erff(x0 * RS2));
  float v1 = 0.5f * x1 * (1.f + erff(x1 * RS2));
  float2 e; e.x = v0; e.y = v1 - v0;
  gtab[i] = e;
}

// circular 8x8 conv, 2 output rows (sq*2, sq*2+1) of one channel.
__device__ __forceinline__ void circ4(const uint32_t* __restrict__ prb,
                                      const float* __restrict__ kc, int sq,
                                      uint32_t* __restrict__ ou) {
  float o[16];
#pragma unroll
  for (int t = 0; t < 16; ++t) o[t] = 0.f;
#pragma unroll 1
  for (int tph = 0; tph < 2; ++tph) {
    float kh[32];
#pragma unroll
    for (int q4 = 0; q4 < 8; ++q4) {
      float4 kv = *(const float4*)(kc + tph * 32 + q4 * 4);
      kh[q4 * 4 + 0] = kv.x; kh[q4 * 4 + 1] = kv.y;
      kh[q4 * 4 + 2] = kv.z; kh[q4 * 4 + 3] = kv.w;
    }
#pragma unroll
    for (int ii = 0; ii < 2; ++ii) {
      int i = sq * 2 + ii;
#pragma unroll
      for (int t4 = 0; t4 < 4; ++t4) {
        int tp = tph * 4 + t4;
        int r = (i - tp) & 7;
        uint2 ua = *(const uint2*)(prb + r * 4);
        uint2 ub = *(const uint2*)(prb + r * 4 + 2);
        float pr[8] = {bflo(ua.x), bfhi(ua.x), bflo(ua.y), bfhi(ua.y),
                       bflo(ub.x), bfhi(ub.x), bflo(ub.y), bfhi(ub.y)};
#pragma unroll
        for (int tq = 0; tq < 8; ++tq) {
          float kv = kh[t4 * 8 + tq];
#pragma unroll
          for (int j = 0; j < 8; ++j)
            o[ii * 8 + j] += kv * pr[(j - tq) & 7];
        }
      }
    }
  }
#pragma unroll
  for (int ii = 0; ii < 2; ++ii) {
    ou[ii * 4 + 0] = f2bfu(o[ii * 8 + 0]) | (f2bfu(o[ii * 8 + 1]) << 16);
    ou[ii * 4 + 1] = f2bfu(o[ii * 8 + 2]) | (f2bfu(o[ii * 8 + 3]) << 16);
    ou[ii * 4 + 2] = f2bfu(o[ii * 8 + 4]) | (f2bfu(o[ii * 8 + 5]) << 16);
    ou[ii * 4 + 3] = f2bfu(o[ii * 8 + 6]) | (f2bfu(o[ii * 8 + 7]) << 16);
  }
}

// ---------------- K1 v9: conv_in 1x1 + bias + patch circular conv ---------
// QUAD-SPLIT (verified R16: ~320us): thread = (cq, sq); 4 channels x 16 px;
// one xs b128 read feeds 16 FMA; (256,2) budget 128 regs, no spill.
__global__ __launch_bounds__(256, 2) void k_front(
    const float* __restrict__ x, const float* __restrict__ w_in,
    const float* __restrict__ b_in, const float* __restrict__ Ks,
    uint32_t* __restrict__ midu) {
  __shared__ __align__(16) uint32_t Au[128 * 34];  // x floats, then ch 0-127
  __shared__ __align__(16) uint32_t Bu[128 * 34];  // ch 128-255
  float* xs = (float*)Au;  // 4096 floats during phases 1-2
  int tid = threadIdx.x;
  int orig = blockIdx.x;
  int pid = (orig & 7) * 1024 + (orig >> 3);  // XCD swizzle (8192 % 8 == 0)
  int b = pid >> 10;
  int pp = pid & 1023;
  int ph = pp >> 5, pw = pp & 31;

  // phase 1: stage x patch (4096 floats) cooperatively, coalesced float4
  {
    const float* xb = x + (size_t)b * 64 * HWSZ + (ph * 8) * 256 + pw * 8;
#pragma unroll
    for (int k = 0; k < 4; ++k) {
      int s = tid + k * 256;
      int d = s >> 4, i = (s >> 1) & 7, jh = s & 1;
      float4 v = *(const float4*)(xb + (size_t)d * HWSZ + i * 256 + jh * 4);
      *(float4*)(xs + d * 64 + i * 8 + jh * 4) = v;
    }
  }
  int sq = tid & 3;   // px quarter: rows sq*2, sq*2+1
  int cq = tid >> 2;  // 0..63
  float p0[16], p1[16], p2[16], p3[16];
  {
    float bi0 = b_in[cq], bi1 = b_in[cq + 64];
    float bi2 = b_in[cq + 128], bi3 = b_in[cq + 192];
#pragma unroll
    for (int t = 0; t < 16; ++t) {
      p0[t] = bi0; p1[t] = bi1; p2[t] = bi2; p3[t] = bi3;
    }
  }
  __syncthreads();

  // phase 2: conv_in, 4 channels x 16 px (1 xs read -> 16 FMA)
  const float* w0 = w_in + cq * 64;
  const float* w1 = w_in + (cq + 64) * 64;
  const float* w2 = w_in + (cq + 128) * 64;
  const float* w3 = w_in + (cq + 192) * 64;
#pragma unroll 1
  for (int d8 = 0; d8 < 8; ++d8) {
    float4 a0 = *(const float4*)(w0 + d8 * 8);
    float4 b0 = *(const float4*)(w0 + d8 * 8 + 4);
    float4 a1 = *(const float4*)(w1 + d8 * 8);
    float4 b1 = *(const float4*)(w1 + d8 * 8 + 4);
    float4 a2 = *(const float4*)(w2 + d8 * 8);
    float4 b2 = *(const float4*)(w2 + d8 * 8 + 4);
    float4 a3 = *(const float4*)(w3 + d8 * 8);
    float4 b3 = *(const float4*)(w3 + d8 * 8 + 4);
    float wv0[8] = {a0.x, a0.y, a0.z, a0.w, b0.x, b0.y, b0.z, b0.w};
    float wv1[8] = {a1.x, a1.y, a1.z, a1.w, b1.x, b1.y, b1.z, b1.w};
    float wv2[8] = {a2.x, a2.y, a2.z, a2.w, b2.x, b2.y, b2.z, b2.w};
    float wv3[8] = {a3.x, a3.y, a3.z, a3.w, b3.x, b3.y, b3.z, b3.w};
#pragma unroll
    for (int dd = 0; dd < 8; ++dd) {
      const float4* xr = (const float4*)(xs + (d8 * 8 + dd) * 64 + sq * 16);
#pragma unroll
      for (int t4 = 0; t4 < 4; ++t4) {
        float4 xv = xr[t4];
        p0[t4 * 4 + 0] += wv0[dd] * xv.x; p1[t4 * 4 + 0] += wv1[dd] * xv.x;
        p2[t4 * 4 + 0] += wv2[dd] * xv.x; p3[t4 * 4 + 0] += wv3[dd] * xv.x;
        p0[t4 * 4 + 1] += wv0[dd] * xv.y; p1[t4 * 4 + 1] += wv1[dd] * xv.y;
        p2[t4 * 4 + 1] += wv2[dd] * xv.y; p3[t4 * 4 + 1] += wv3[dd] * xv.y;
        p0[t4 * 4 + 2] += wv0[dd] * xv.z; p1[t4 * 4 + 2] += wv1[dd] * xv.z;
        p2[t4 * 4 + 2] += wv2[dd] * xv.z; p3[t4 * 4 + 2] += wv3[dd] * xv.z;
        p0[t4 * 4 + 3] += wv0[dd] * xv.w; p1[t4 * 4 + 3] += wv1[dd] * xv.w;
        p2[t4 * 4 + 3] += wv2[dd] * xv.w; p3[t4 * 4 + 3] += wv3[dd] * xv.w;
      }
    }
  }
  __syncthreads();  // all conv_in reads of xs done before bf16 overwrite

  // phase 3: pack p -> bf16 pairs into channel rows (8 uints @ sq*8)
  {
    uint32_t* r0 = Au + cq * 34 + sq * 8;
    uint32_t* r1 = Au + (cq + 64) * 34 + sq * 8;
    uint32_t* r2 = Bu + cq * 34 + sq * 8;
    uint32_t* r3 = Bu + (cq + 64) * 34 + sq * 8;
#pragma unroll
    for (int m = 0; m < 4; ++m) {
      uint2 u0, u1, u2, u3;
      u0.x = f2bfu(p0[m * 4 + 0]) | (f2bfu(p0[m * 4 + 1]) << 16);
      u0.y = f2bfu(p0[m * 4 + 2]) | (f2bfu(p0[m * 4 + 3]) << 16);
      u1.x = f2bfu(p1[m * 4 + 0]) | (f2bfu(p1[m * 4 + 1]) << 16);
      u1.y = f2bfu(p1[m * 4 + 2]) | (f2bfu(p1[m * 4 + 3]) << 16);
      u2.x = f2bfu(p2[m * 4 + 0]) | (f2bfu(p2[m * 4 + 1]) << 16);
      u2.y = f2bfu(p2[m * 4 + 2]) | (f2bfu(p2[m * 4 + 3]) << 16);
      u3.x = f2bfu(p3[m * 4 + 0]) | (f2bfu(p3[m * 4 + 1]) << 16);
      u3.y = f2bfu(p3[m * 4 + 2]) | (f2bfu(p3[m * 4 + 3]) << 16);
      *(uint2*)(r0 + m * 2) = u0;
      *(uint2*)(r1 + m * 2) = u1;
      *(uint2*)(r2 + m * 2) = u2;
      *(uint2*)(r3 + m * 2) = u3;
    }
  }
  __syncthreads();  // all p rows visible before circ conv

  // phase 4: circ conv, 4 channels sequential; ONE barrier, then write-back
  uint32_t ou[4][8];
  circ4(Au + cq * 34, Ks + cq * 64, sq, ou[0]);
  circ4(Au + (cq + 64) * 34, Ks + (cq + 64) * 64, sq, ou[1]);
  circ4(Bu + cq * 34, Ks + (cq + 128) * 64, sq, ou[2]);
  circ4(Bu + (cq + 64) * 34, Ks + (cq + 192) * 64, sq, ou[3]);
  __syncthreads();  // all reads of Au/Bu complete
  {
    uint32_t* r0 = Au + cq * 34 + sq * 8;
    uint32_t* r1 = Au + (cq + 64) * 34 + sq * 8;
    uint32_t* r2 = Bu + cq * 34 + sq * 8;
    uint32_t* r3 = Bu + (cq + 64) * 34 + sq * 8;
#pragma unroll
    for (int m = 0; m < 4; ++m) {
      uint2 u0; u0.x = ou[0][m * 2 + 0]; u0.y = ou[0][m * 2 + 1];
      uint2 u1; u1.x = ou[1][m * 2 + 0]; u1.y = ou[1][m * 2 + 1];
      uint2 u2; u2.x = ou[2][m * 2 + 0]; u2.y = ou[2][m * 2 + 1];
      uint2 u3; u3.x = ou[3][m * 2 + 0]; u3.y = ou[3][m * 2 + 1];
      *(uint2*)(r0 + m * 2) = u0;
      *(uint2*)(r1 + m * 2) = u1;
      *(uint2*)(r2 + m * 2) = u2;
      *(uint2*)(r3 + m * 2) = u3;
    }
  }
  __syncthreads();

  // phase 6: cooperative fully-coalesced write: 8192 uints (32 KB) / block
  uint32_t* gbase = midu + (size_t)(b * 1024 + pp) * 8192;
#pragma unroll
  for (int k = 0; k < 8; ++k) {
    int g = tid * 4 + k * 1024;
    int w = g & 31;
    uint2 a, e;
    if (k < 4) {  // channels 0..127 live in Au (uniform branch: k static)
      int cc = g >> 5;
      a = *(uint2*)(Au + cc * 34 + w);
      e = *(uint2*)(Au + cc * 34 + w + 2);
    } else {      // channels 128..255 in Bu
      int cc = (g >> 5) - 128;
      a = *(uint2*)(Bu + cc * 34 + w);
      e = *(uint2*)(Bu + cc * 34 + w + 2);
    }
    uint4 q; q.x = a.x; q.y = a.y; q.z = e.x; q.w = e.y;
    *(uint4*)(gbase + g) = q;
  }
}

// ---------------- K2 v13 (R18, final): dw7x7 + GELU(table) + conv_out -----
// Verified best (865us): TUB=48 (2 lanes/bank reads), DMA weight staging,
// LDS-table GELU, pk_fma conv_out, VGPR 112 (+128 acc = 240 -> 2 blk/CU).
// R19-R21 tested d-split / barrier-halving / setprio+chain-split: all
// neutral or regressed; this structure is the measured optimum.
#define TUB 48
__global__ __launch_bounds__(256, 1) void k_back(
    const uint32_t* __restrict__ midu, const float* __restrict__ wdwp,
    const float* __restrict__ wT, const float* __restrict__ b_out,
    const float2* __restrict__ gtab, float* __restrict__ out) {
  __shared__ __align__(16) uint32_t tile[2][22 * TUB];  // 8448 B
  __shared__ __align__(16) float wbuf[2][128];  // [0..63]=wdwp, [64..127]=wT
  __shared__ __align__(16) float2 gt[1024];     // 8192 B gelu table
  int t = threadIdx.x;
  int orig = blockIdx.x;
  int pid = (orig & 7) * 128 + (orig >> 3);  // XCD swizzle (1024 % 8 == 0)
  int b = pid >> 7;
  int tb = pid & 127;
  int th = tb >> 3, tw = tb & 7;  // 16 row-tiles x 8 col-tiles
  int R0 = th * 16, C0 = tw * 32;

  // copy gelu table to LDS (coalesced, one-time)
#pragma unroll
  for (int i = 0; i < 4; ++i) gt[t + i * 256] = gtab[t + i * 256];

  // zero-init both tile buffers; out-of-image slots stay zero
  for (int z = t; z < 2 * 22 * TUB; z += 256) ((uint32_t*)tile)[z] = 0u;

  // tile loader lanes: t<176: lr = t>>3 (row 0..21), p = t&7 (quad idx)
  int lr = t >> 3, p = t & 7;
  int g = R0 - 3 + lr;          // global px row
  int pc = 4 * tw - 1 + p;      // global patch col of own quad
  bool aw = (t < 176) && (p < 6) && ((unsigned)g < 256u);  // writer lane
  bool qv = aw && ((unsigned)pc < 32u);                    // own quad valid
  size_t src0 = 0;
  if (qv)
    src0 = ((size_t)(b * 1024 + (g >> 3) * 32 + pc) * 8192) +
           (size_t)((g & 7) * 4);

  int ty = t >> 4, tx = t & 15;
  int lane = t - 192;  // wave-3 lane id (valid when t >= 192)

  v2f acc[64];
#pragma unroll
  for (int d = 0; d < 64; ++d) acc[d] = (v2f)(0.f);

  __syncthreads();  // zero-init + table copy complete before prologue

  // prologue: stage channel 0 (tile by t<176; weights DMA'd by wave 3)
  {
    uint4 q; q.x = 0u; q.y = 0u; q.z = 0u; q.w = 0u;
    if (qv) q = *(const uint4*)(midu + src0);
    uint32_t ex = (uint32_t)__shfl_down((int)q.x, 1);  // neighbor quad word0
    if (aw) {
      uint32_t* dr = &tile[0][0] + lr * TUB;
      uint32_t w0 = (q.x >> 16) | (q.y << 16);  // k = 4p-2
      uint32_t w1 = (q.y >> 16) | (q.z << 16);  // k = 4p-1
      uint32_t w2 = (q.z >> 16) | (q.w << 16);  // k = 4p
      uint32_t w3 = (q.w >> 16) | (ex << 16);   // k = 4p+1
      if (p == 0) {
        uint2 hb; hb.x = w2; hb.y = w3;   // k = 0,1
        *(uint2*)(dr + 0) = hb;
      } else if (p == 5) {
        dr[18] = w0;                      // k = 18
      } else {
        uint2 ha; ha.x = w0; ha.y = w1;
        uint2 hb; hb.x = w2; hb.y = w3;
        *(uint2*)(dr + 4 * p - 2) = ha;   // k = 4p-2, 4p-1
        *(uint2*)(dr + 4 * p) = hb;       // k = 4p,   4p+1
      }
    }
    if (t >= 192) {  // wave-uniform: whole wave 3
      __builtin_amdgcn_global_load_lds(
          (const __attribute__((address_space(1))) uint32_t*)(wdwp + lane),
          (__attribute__((address_space(3))) uint32_t*)&wbuf[0][0], 4, 0, 0);
      __builtin_amdgcn_global_load_lds(
          (const __attribute__((address_space(1))) uint32_t*)(wT + lane),
          (__attribute__((address_space(3))) uint32_t*)&wbuf[0][64], 4, 0, 0);
    }
  }
  __syncthreads();

  for (int c = 0; c < 256; ++c) {
    int cur = c & 1;
    bool pf = (c < 255);  // uniform
    // tile prefetch for c+1 (registers, as in R8)
    uint4 q; q.x = 0u; q.y = 0u; q.z = 0u; q.w = 0u;
    if (pf && qv) q = *(const uint4*)(midu + src0 + (size_t)(c + 1) * 32);
    // weight prefetch for c+1: zero-VGPR DMA into wbuf[cur^1]
    if (pf && t >= 192) {
      const float* wds = wdwp + (size_t)(c + 1) * 64 + lane;
      const float* wts = wT + (size_t)(c + 1) * 64 + lane;
      __builtin_amdgcn_global_load_lds(
          (const __attribute__((address_space(1))) uint32_t*)wds,
          (__attribute__((address_space(3))) uint32_t*)&wbuf[cur ^ 1][0],
          4, 0, 0);
      __builtin_amdgcn_global_load_lds(
          (const __attribute__((address_space(1))) uint32_t*)wts,
          (__attribute__((address_space(3))) uint32_t*)&wbuf[cur ^ 1][64],
          4, 0, 0);
    }

    const uint32_t* tl = &tile[cur][0];
    const float* wl = wbuf[cur];
    float s0 = wl[55], s1 = s0;  // bias (broadcast ds_read)
#pragma unroll
    for (int u = 0; u < 7; ++u) {
      const uint32_t* row = tl + (ty + u) * TUB + tx;
      uint32_t k0 = row[0], k1 = row[1], k2 = row[2], k3 = row[3];
      float f0 = bflo(k0), f1 = bfhi(k0), f2 = bflo(k1), f3 = bfhi(k1);
      float f4 = bflo(k2), f5 = bfhi(k2), f6 = bflo(k3), f7 = bfhi(k3);
      float4 wA = *(const float4*)(wl + u * 8);      // taps 0-3 (broadcast)
      float4 wB = *(const float4*)(wl + u * 8 + 4);  // taps 4-6 + pad
      s0 += wA.x * f0 + wA.y * f1 + wA.z * f2 + wA.w * f3 + wB.x * f4 +
            wB.y * f5 + wB.z * f6;
      s1 += wA.x * f1 + wA.y * f2 + wA.z * f3 + wA.w * f4 + wB.x * f5 +
            wB.y * f6 + wB.z * f7;
    }
    // GELU via LDS table: idx = s*(1024/12)+512, linear interp
    const float GSC = 85.333333333333f;  // 1024/12
    float u0 = fminf(fmaxf(fmaf(s0, GSC, 512.f), 0.f), 1023.f);
    float u1 = fminf(fmaxf(fmaf(s1, GSC, 512.f), 0.f), 1023.f);
    int i0 = (int)u0, i1 = (int)u1;
    float2 e0 = gt[i0];
    float2 e1 = gt[i1];
    v2f g2;
    g2.x = fmaf(e0.y, u0 - (float)i0, e0.x);
    g2.y = fmaf(e1.y, u1 - (float)i1, e1.x);

    // conv_out: v_pk_fma_f32 — one instruction covers both pixels
    const float* wcl = wl + 64;
#pragma unroll
    for (int d4 = 0; d4 < 16; ++d4) {
      float4 wv = *(const float4*)(wcl + d4 * 4);  // broadcast ds_read_b128
      acc[d4 * 4 + 0] += g2 * wv.x;
      acc[d4 * 4 + 1] += g2 * wv.y;
      acc[d4 * 4 + 2] += g2 * wv.z;
      acc[d4 * 4 + 3] += g2 * wv.w;
    }

    if (pf) {
      uint32_t ex = (uint32_t)__shfl_down((int)q.x, 1);
      if (aw) {
        uint32_t* dr = &tile[cur ^ 1][0] + lr * TUB;
        uint32_t w0 = (q.x >> 16) | (q.y << 16);
        uint32_t w1 = (q.y >> 16) | (q.z << 16);
        uint32_t w2 = (q.z >> 16) | (q.w << 16);
        uint32_t w3 = (q.w >> 16) | (ex << 16);
        if (p == 0) {
          uint2 hb; hb.x = w2; hb.y = w3;
          *(uint2*)(dr + 0) = hb;
        } else if (p == 5) {
          dr[18] = w0;
        } else {
          uint2 ha; ha.x = w0; ha.y = w1;
          uint2 hb; hb.x = w2; hb.y = w3;
          *(uint2*)(dr + 4 * p - 2) = ha;
          *(uint2*)(dr + 4 * p) = hb;
        }
      }
    }
    __syncthreads();
  }

  // coalesced 8B stores: lanes cover consecutive spans of each row
  size_t obase = (size_t)b * 64 * HWSZ + (size_t)(R0 + ty) * 256 + C0 + 2 * tx;
#pragma unroll
  for (int d = 0; d < 64; ++d) {
    v2f r = acc[d] + b_out[d];  // b_out uniform -> s_load; packed add
    *(v2f*)(out + obase + (size_t)d * HWSZ) = r;
  }
}

extern "C" void kernel_launch(void* const* d_in, const int* in_sizes, int n_in,
                              void* d_out, int out_size, void* d_ws, size_t ws_size,
                              hipStream_t stream) {
  (void)in_sizes; (void)n_in; (void)out_size; (void)ws_size;
  const float* x     = (const float*)d_in[0];
  const float* w_in  = (const float*)d_in[1];
  const float* b_in  = (const float*)d_in[2];
  const float* fftf  = (const float*)d_in[3];
  const float* w_dw  = (const float*)d_in[4];
  const float* b_dw  = (const float*)d_in[5];
  const float* w_out = (const float*)d_in[6];
  const float* b_out = (const float*)d_in[7];
  float* out = (float*)d_out;

  float* Ks = (float*)d_ws;                                   // 64 KB
  float* wT = (float*)((char*)d_ws + 65536);                  // 64 KB
  float* wdwp = (float*)((char*)d_ws + 131072);               // 64 KB
  float2* gtab = (float2*)((char*)d_ws + 196608);             // 8 KB
  uint32_t* midu = (uint32_t*)((char*)d_ws + 204800);         // 268 MB

  k_prep<<<256, 64, 0, stream>>>(fftf, Ks);
  k_wt<<<256, 64, 0, stream>>>(w_out, wT);
  k_wdw<<<256, 64, 0, stream>>>(w_dw, b_dw, wdwp);
  k_gt<<<4, 256, 0, stream>>>(gtab);
  k_front<<<8192, 256, 0, stream>>>(x, w_in, b_in, Ks, midu);
  k_back<<<1024, 256, 0, stream>>>(midu, wdwp, wT, b_out, gtab, out);
}